// Round 4
// baseline (886.741 us; speedup 1.0000x reference)
//
#include <hip/hip_runtime.h>
#include <hip/hip_bf16.h>
#include <math.h>

// ============================================================================
// AuroraBlock round 4: single fused kernel for all 4 reasoning steps.
//   - 1 wave = 1 position, r in VGPRs across all steps (no r_cur traffic).
//   - residual adds folded into MFMA C-accumulation (mask folded into the
//     bf16 B operand) -> no c2[16]/fo[16] accumulator arrays (saves 64 VGPR).
//   - weight stream: 1536 frags (1KB each) in consumption order; staged in
//     8KB chunks, ring-4 LDS (32KB), counted vmcnt(4) + raw s_barrier.
//     768 boundaries total (192/step), each phase consumes exactly 8 frags.
//   - compiler bf16 casts (v_cvt_pk), amdgcn rcp for divisions, s_setprio.
// ws (floats): [0..65535] mask | [65536..69631] sproj | [69632..81919] probs
//   [81920..81923] accum | shorts at float offset 131072:
//   Wstream(786432) PWa1(32768) PWd1(131072)
// d_out: [0..16777215] r_out, [16777216] routing_loss, [16777217] mean_k
// ============================================================================

#define NPOS 4096
#define R_ELEMS 16777216ull
#define NB 768  // total boundaries = 192 per step * 4 steps

typedef __attribute__((ext_vector_type(8))) short short8;
typedef __attribute__((ext_vector_type(4))) float f32x4;

#define MF(a, b, c) __builtin_amdgcn_mfma_f32_16x16x32_bf16(a, b, c, 0, 0, 0)

__device__ __forceinline__ short bf16rne(float f) {
  union { float f; unsigned u; } v; v.f = f;
  unsigned r = v.u + 0x7FFFu + ((v.u >> 16) & 1u);
  return (short)(r >> 16);
}

__device__ __forceinline__ short bf16c(float f) {
  __hip_bfloat16 h = __float2bfloat16(f);
  return *reinterpret_cast<short*>(&h);
}

__device__ __forceinline__ float fast_gelu(float x) {
  float x2 = x * x;
  float z = 0.7978845608028654f * x * (1.f + 0.044715f * x2);
  float e = __expf(2.f * z);  // tanh(z) = 1 - 2/(e^{2z}+1)
  float t = 1.f - 2.f * __builtin_amdgcn_rcpf(e + 1.f);
  return 0.5f * x * (1.f + t);
}

// ---- packing for difficulty/slot_mask (fragment-array layout) ----
__global__ void pack_weight(const float* __restrict__ W, short* __restrict__ P,
                            int K, int N) {
  int id = blockIdx.x * 256 + threadIdx.x;
  int KC = K >> 5, T = N >> 4;
  if (id >= T * KC * 64) return;
  int l = id & 63, kc = (id >> 6) % KC, t = id / (64 * KC);
  int g = l >> 4, n = l & 15;
  short8 o;
#pragma unroll
  for (int jj = 0; jj < 8; jj++) {
    int k = 32 * kc + 4 * g + (jj & 3) + 16 * (jj >> 2);
    o[jj] = bf16rne(W[(size_t)k * N + 16 * t + n]);
  }
  *(short8*)(P + (size_t)id * 8) = o;
}

// ---- pack reasoning weights into consumption-order stream (as round 3) ----
__global__ void pack_stream(const float* __restrict__ Wq, const float* __restrict__ Wk,
                            const float* __restrict__ Wv, const float* __restrict__ Wo,
                            const float* __restrict__ Wf1, const float* __restrict__ Wf2,
                            short* __restrict__ S) {
  int id = blockIdx.x * 256 + threadIdx.x;
  int f = id >> 6, lane = id & 63;
  if (f >= 1536) return;
  const float* W; int ldN, t, kc;
  if (f < 384) {
    int hh = f / 96, rem = f % 96, mat = rem / 32, r2 = rem % 32;
    t = 4 * hh + r2 / 8; kc = r2 % 8; ldN = 256;
    W = (mat == 0) ? Wq : (mat == 1) ? Wk : Wv;
  } else if (f < 512) {
    int gg = f - 384; t = gg / 8; kc = gg % 8; ldN = 256; W = Wo;
  } else {
    int gg = f - 512, hc = gg / 32, r2 = gg % 32;
    if (r2 < 16) { W = Wf1; ldN = 1024; t = 2 * hc + r2 / 8; kc = r2 % 8; }
    else         { W = Wf2; ldN = 256;  t = r2 - 16;         kc = hc;    }
  }
  int g = lane >> 4, n = lane & 15;
  short8 o;
#pragma unroll
  for (int jj = 0; jj < 8; jj++) {
    int k = 32 * kc + 4 * g + (jj & 3) + 16 * (jj >> 2);
    o[jj] = bf16rne(W[(size_t)k * ldN + 16 * t + n]);
  }
  *(short8*)(S + (size_t)f * 512 + lane * 8) = o;
}

__device__ __forceinline__ short8 ldfrag(const short* __restrict__ P, int t, int kc,
                                         int KC, int lane) {
  return *(const short8*)(P + ((size_t)((t * KC + kc) * 64 + lane) << 3));
}

__global__ void init_accum_kernel(float* accum) {
  if (threadIdx.x < 4) accum[threadIdx.x] = 0.f;
}

__global__ void sproj_kernel(const float* __restrict__ s, const float* __restrict__ Ws,
                             float* __restrict__ sproj) {
  int p = blockIdx.x, tid = threadIdx.x;
  const float* row = s + (size_t)p * 1024;
  float sum = 0.f;
#pragma unroll
  for (int k0 = 0; k0 < 1024; k0 += 256) sum += row[k0 + tid] * Ws[k0 + tid];
#pragma unroll
  for (int m = 1; m < 64; m <<= 1) sum += __shfl_xor(sum, m, 64);
  __shared__ float red[4];
  if ((tid & 63) == 0) red[tid >> 6] = sum;
  __syncthreads();
  if (tid == 0) sproj[p] = red[0] + red[1] + red[2] + red[3];
}

__global__ void difficulty_mfma(const float* __restrict__ s, const short* __restrict__ PWd1,
                                const float* __restrict__ bd1, const float* __restrict__ Wd2,
                                const float* __restrict__ bd2, float* __restrict__ probsv,
                                float* __restrict__ accum) {
  int tid = threadIdx.x;
  int wave = tid >> 6, lane = tid & 63, n = lane & 15, g = lane >> 4;
  int p0 = (blockIdx.x * 4 + wave) * 16;
  const float* sg = s + (size_t)(p0 + n) * 1024;
  f32x4 ha[8];
  const f32x4 Z = {0.f, 0.f, 0.f, 0.f};
#pragma unroll
  for (int t = 0; t < 8; t++) ha[t] = Z;
  for (int kc = 0; kc < 32; kc++) {
    f32x4 x0 = *(const f32x4*)(sg + 32 * kc + 4 * g);
    f32x4 x1 = *(const f32x4*)(sg + 32 * kc + 16 + 4 * g);
    short8 sb;
#pragma unroll
    for (int c = 0; c < 4; c++) { sb[c] = bf16c(x0[c]); sb[c + 4] = bf16c(x1[c]); }
#pragma unroll
    for (int t = 0; t < 8; t++) ha[t] = MF(ldfrag(PWd1, t, kc, 32, lane), sb, ha[t]);
  }
  float v0 = 0.f, v1 = 0.f, v2 = 0.f;
#pragma unroll
  for (int t = 0; t < 8; t++)
#pragma unroll
    for (int c = 0; c < 4; c++) {
      int hid = 16 * t + 4 * g + c;
      float u = fmaxf(ha[t][c] + bd1[hid], 0.f);
      v0 += u * Wd2[hid * 3 + 0];
      v1 += u * Wd2[hid * 3 + 1];
      v2 += u * Wd2[hid * 3 + 2];
    }
  v0 += __shfl_xor(v0, 16, 64); v0 += __shfl_xor(v0, 32, 64);
  v1 += __shfl_xor(v1, 16, 64); v1 += __shfl_xor(v1, 32, 64);
  v2 += __shfl_xor(v2, 16, 64); v2 += __shfl_xor(v2, 32, 64);
  if (g == 0) {
    float l0 = v0 + bd2[0], l1 = v1 + bd2[1], l2 = v2 + bd2[2];
    float mx = fmaxf(l0, fmaxf(l1, l2));
    float e0 = __expf(l0 - mx), e1 = __expf(l1 - mx), e2 = __expf(l2 - mx);
    float inv = 1.f / (e0 + e1 + e2);
    float p0v = e0 * inv, p1v = e1 * inv, p2v = e2 * inv;
    int p = p0 + n;
    probsv[p * 3 + 0] = p0v; probsv[p * 3 + 1] = p1v; probsv[p * 3 + 2] = p2v;
    atomicAdd(accum + 0, p0v);
    atomicAdd(accum + 1, p1v);
    atomicAdd(accum + 2, p2v);
    atomicAdd(accum + 3, p0v * 1.f + p1v * 2.f + p2v * 4.f);
  }
}

__global__ void slot_mask_mfma(const float* __restrict__ r, const short* __restrict__ PWa1,
                               const float* __restrict__ ba1, const float* __restrict__ Wa2,
                               const float* __restrict__ ba2, const float* __restrict__ sproj,
                               float* __restrict__ mask) {
  int tid = threadIdx.x;
  int wave = tid >> 6, lane = tid & 63, n = lane & 15, g = lane >> 4;
  int p = blockIdx.x * 4 + wave;
  const float* rsg = r + (size_t)p * 4096 + n * 256;
  short8 rb[8];
#pragma unroll
  for (int kc = 0; kc < 8; kc++) {
    f32x4 x0 = *(const f32x4*)(rsg + 32 * kc + 4 * g);
    f32x4 x1 = *(const f32x4*)(rsg + 32 * kc + 16 + 4 * g);
    short8 o;
#pragma unroll
    for (int c = 0; c < 4; c++) { o[c] = bf16c(x0[c]); o[c + 4] = bf16c(x1[c]); }
    rb[kc] = o;
  }
  f32x4 ha[8];
  const f32x4 Z = {0.f, 0.f, 0.f, 0.f};
#pragma unroll
  for (int t = 0; t < 8; t++) ha[t] = Z;
#pragma unroll
  for (int kc = 0; kc < 8; kc++)
#pragma unroll
    for (int t = 0; t < 8; t++) ha[t] = MF(ldfrag(PWa1, t, kc, 8, lane), rb[kc], ha[t]);
  float v = 0.f;
#pragma unroll
  for (int t = 0; t < 8; t++)
#pragma unroll
    for (int c = 0; c < 4; c++) {
      int hid = 16 * t + 4 * g + c;
      v += fmaxf(ha[t][c] + ba1[hid], 0.f) * Wa2[hid];
    }
  v += __shfl_xor(v, 16, 64);
  v += __shfl_xor(v, 32, 64);
  if (g == 0) mask[p * 16 + n] = 1.f / (1.f + __expf(-(v + ba2[0] + sproj[p])));
}

// ===================== fused 4-step reasoning kernel ========================
__global__ __launch_bounds__(256, 3) void reason_all(
    const float* __restrict__ r_src, const float* __restrict__ maskg,
    const float* __restrict__ probsv, float* __restrict__ outp,
    const short* __restrict__ Wstream,
    const float* __restrict__ ln1s, const float* __restrict__ ln1b,
    const float* __restrict__ ln2s, const float* __restrict__ ln2b,
    const float* __restrict__ bf1g, const float* __restrict__ bf2g) {
  __shared__ __align__(16) short Wbuf[4 * 4096];  // 4 x 8KB ring = 32KB
  __shared__ __align__(16) float P_ln1s[256], P_ln1b[256], P_ln2s[256], P_ln2b[256];
  __shared__ __align__(16) float P_bf1[1024], P_bf2[256];
  const int tid = threadIdx.x;
  P_ln1s[tid] = ln1s[tid]; P_ln1b[tid] = ln1b[tid];
  P_ln2s[tid] = ln2s[tid]; P_ln2b[tid] = ln2b[tid];
  P_bf2[tid] = bf2g[tid];
  for (int i = tid; i < 1024; i += 256) P_bf1[i] = bf1g[i];
  __syncthreads();

  const int wave = tid >> 6, lane = tid & 63;
  const int n = lane & 15, g = lane >> 4;
  const int p = blockIdx.x * 4 + wave;
  const size_t base = (size_t)p * 4096;
  const f32x4 Z = {0.f, 0.f, 0.f, 0.f};

  // ---- staging machinery: 8KB chunks, ring 4, 2 loads/thread/chunk ----
  auto stage_issue = [&](int c) {
    const short* gs = Wstream + (size_t)(c % 192) * 4096 + wave * 1024 + lane * 8;
    short* ld = (short*)Wbuf + (c & 3) * 4096 + wave * 1024;  // wave-uniform dest
#pragma unroll
    for (int i = 0; i < 2; ++i)
      __builtin_amdgcn_global_load_lds(
          (const __attribute__((address_space(1))) void*)(gs + i * 512),
          (__attribute__((address_space(3))) void*)(ld + i * 512), 16, 0, 0);
  };
  stage_issue(0); stage_issue(1); stage_issue(2);

  // ---- prologue: r -> regs; mask & candidate weights ----
  f32x4 r0[8], r1[8];
  {
    const float* rsg = r_src + base + n * 256;
#pragma unroll
    for (int kc = 0; kc < 8; kc++) {
      r0[kc] = *(const f32x4*)(rsg + 32 * kc + 4 * g);
      r1[kc] = *(const f32x4*)(rsg + 32 * kc + 16 + 4 * g);
    }
  }
  const float maskn = maskg[p * 16 + n];
  const float w0 = probsv[p * 3 + 0];
  const float w1 = probsv[p * 3 + 1];
  const float w2 = probsv[p * 3 + 2];

  int cidx = 0;
  auto boundary = [&]() -> const short* {
    int c = cidx++;
    if (c <= NB - 3)
      asm volatile("s_waitcnt vmcnt(4) lgkmcnt(0)\ns_barrier" ::: "memory");
    else if (c == NB - 2)
      asm volatile("s_waitcnt vmcnt(2) lgkmcnt(0)\ns_barrier" ::: "memory");
    else
      asm volatile("s_waitcnt vmcnt(0) lgkmcnt(0)\ns_barrier" ::: "memory");
    __builtin_amdgcn_sched_barrier(0);
    if (c + 3 < NB) stage_issue(c + 3);
    return &Wbuf[(c & 3) * 4096];
  };
#define FRAG(Bp, i) (*(const short8*)((Bp) + (i) * 512 + lane * 8))

  short8 h1[8];
  auto do_ln = [&](const float* sc, const float* bi) {
    float sum = 0.f, sq = 0.f;
#pragma unroll
    for (int kc = 0; kc < 8; kc++)
#pragma unroll
      for (int c = 0; c < 4; c++) {
        sum += r0[kc][c] + r1[kc][c];
        sq += r0[kc][c] * r0[kc][c] + r1[kc][c] * r1[kc][c];
      }
    sum += __shfl_xor(sum, 16, 64); sq += __shfl_xor(sq, 16, 64);
    sum += __shfl_xor(sum, 32, 64); sq += __shfl_xor(sq, 32, 64);
    float mu = sum * (1.f / 256.f);
    float inv = rsqrtf(sq * (1.f / 256.f) - mu * mu + 1e-5f);
#pragma unroll
    for (int kc = 0; kc < 8; kc++) {
      f32x4 s0 = *(const f32x4*)&sc[32 * kc + 4 * g];
      f32x4 b0 = *(const f32x4*)&bi[32 * kc + 4 * g];
      f32x4 s1 = *(const f32x4*)&sc[32 * kc + 16 + 4 * g];
      f32x4 b1 = *(const f32x4*)&bi[32 * kc + 16 + 4 * g];
      short8 hh;
#pragma unroll
      for (int c = 0; c < 4; c++) {
        hh[c]     = bf16c((r0[kc][c] - mu) * inv * s0[c] + b0[c]);
        hh[c + 4] = bf16c((r1[kc][c] - mu) * inv * s1[c] + b1[c]);
      }
      h1[kc] = hh;
    }
  };

  for (int sidx = 0; sidx < 4; ++sidx) {
    // ================= attention =================
    do_ln(P_ln1s, P_ln1b);

    short8 ob[8];
#pragma unroll 1
    for (int hh = 0; hh < 4; hh++) {
      short8 qb[2], kb[2];
      f32x4 va[4];
      {
        f32x4 qa[4];
#pragma unroll
        for (int t = 0; t < 4; t++) {
          const short* B = boundary();
          qa[t] = Z;
          __builtin_amdgcn_s_setprio(1);
#pragma unroll
          for (int kc = 0; kc < 8; kc++) qa[t] = MF(FRAG(B, kc), h1[kc], qa[t]);
          __builtin_amdgcn_s_setprio(0);
        }
#pragma unroll
        for (int c = 0; c < 2; c++) {
          short8 x;
#pragma unroll
          for (int jj = 0; jj < 8; jj++) x[jj] = bf16c(qa[2 * c + (jj >> 2)][jj & 3]);
          qb[c] = x;
        }
      }
      {
        f32x4 ka[4];
#pragma unroll
        for (int t = 0; t < 4; t++) {
          const short* B = boundary();
          ka[t] = Z;
          __builtin_amdgcn_s_setprio(1);
#pragma unroll
          for (int kc = 0; kc < 8; kc++) ka[t] = MF(FRAG(B, kc), h1[kc], ka[t]);
          __builtin_amdgcn_s_setprio(0);
        }
#pragma unroll
        for (int c = 0; c < 2; c++) {
          short8 x;
#pragma unroll
          for (int jj = 0; jj < 8; jj++) x[jj] = bf16c(ka[2 * c + (jj >> 2)][jj & 3]);
          kb[c] = x;
        }
      }
#pragma unroll
      for (int t = 0; t < 4; t++) {
        const short* B = boundary();
        va[t] = Z;
        __builtin_amdgcn_s_setprio(1);
#pragma unroll
        for (int kc = 0; kc < 8; kc++) va[t] = MF(h1[kc], FRAG(B, kc), va[t]);
        __builtin_amdgcn_s_setprio(0);
      }
      // scores^T (per head), softmax over rows, PV — as round 2/3
      f32x4 sc = Z;
      sc = MF(kb[0], qb[0], sc);
      sc = MF(kb[1], qb[1], sc);
#pragma unroll
      for (int c = 0; c < 4; c++) sc[c] *= 0.125f;
      float mx = fmaxf(fmaxf(sc[0], sc[1]), fmaxf(sc[2], sc[3]));
      mx = fmaxf(mx, __shfl_xor(mx, 16, 64));
      mx = fmaxf(mx, __shfl_xor(mx, 32, 64));
      float e0 = __expf(sc[0] - mx), e1 = __expf(sc[1] - mx);
      float e2 = __expf(sc[2] - mx), e3 = __expf(sc[3] - mx);
      float sm = e0 + e1 + e2 + e3;
      sm += __shfl_xor(sm, 16, 64);
      sm += __shfl_xor(sm, 32, 64);
      float isv = __builtin_amdgcn_rcpf(sm);
      short8 pb;
      pb[0] = bf16c(e0 * isv); pb[1] = bf16c(e1 * isv);
      pb[2] = bf16c(e2 * isv); pb[3] = bf16c(e3 * isv);
      pb[4] = 0; pb[5] = 0; pb[6] = 0; pb[7] = 0;
      short8 vb[4];
#pragma unroll
      for (int t = 0; t < 4; t++) {
        short8 x;
        x[0] = bf16c(va[t][0]); x[1] = bf16c(va[t][1]);
        x[2] = bf16c(va[t][2]); x[3] = bf16c(va[t][3]);
        x[4] = 0; x[5] = 0; x[6] = 0; x[7] = 0;
        vb[t] = x;
      }
      f32x4 oh[4];
#pragma unroll
      for (int t = 0; t < 4; t++) { oh[t] = Z; oh[t] = MF(vb[t], pb, oh[t]); }
      // fold mask into o-operand (residual via MFMA C-accum in Wo phases)
#pragma unroll
      for (int c = 0; c < 2; c++) {
        short8 x;
#pragma unroll
        for (int jj = 0; jj < 8; jj++)
          x[jj] = bf16c(maskn * oh[2 * c + (jj >> 2)][jj & 3]);
        ob[2 * hh + c] = x;
      }
    }

    // ---- r += (maskn*o) @ Wo  (accumulate directly into r tiles) ----
#pragma unroll
    for (int kk = 0; kk < 8; kk++) {
      {
        const short* B = boundary();
        __builtin_amdgcn_s_setprio(1);
#pragma unroll
        for (int kc = 0; kc < 8; kc++) r0[kk] = MF(FRAG(B, kc), ob[kc], r0[kk]);
        __builtin_amdgcn_s_setprio(0);
      }
      {
        const short* B = boundary();
        __builtin_amdgcn_s_setprio(1);
#pragma unroll
        for (int kc = 0; kc < 8; kc++) r1[kk] = MF(FRAG(B, kc), ob[kc], r1[kk]);
        __builtin_amdgcn_s_setprio(0);
      }
    }

    // ================= FFN =================
    do_ln(P_ln2s, P_ln2b);
#pragma unroll 1
    for (int hc = 0; hc < 32; hc++) {
      f32x4 ht0 = Z, ht1 = Z;
      {
        const short* B = boundary();
        __builtin_amdgcn_s_setprio(1);
#pragma unroll
        for (int kc = 0; kc < 8; kc++) ht0 = MF(FRAG(B, kc), h1[kc], ht0);
        __builtin_amdgcn_s_setprio(0);
      }
      {
        const short* B = boundary();
        __builtin_amdgcn_s_setprio(1);
#pragma unroll
        for (int kc = 0; kc < 8; kc++) ht1 = MF(FRAG(B, kc), h1[kc], ht1);
        __builtin_amdgcn_s_setprio(0);
      }
      f32x4 u0 = *(const f32x4*)&P_bf1[32 * hc + 4 * g];
      f32x4 u1 = *(const f32x4*)&P_bf1[32 * hc + 16 + 4 * g];
      short8 hbb;
#pragma unroll
      for (int c = 0; c < 4; c++) {
        hbb[c]     = bf16c(maskn * fast_gelu(ht0[c] + u0[c]));
        hbb[c + 4] = bf16c(maskn * fast_gelu(ht1[c] + u1[c]));
      }
      {
        const short* B = boundary();  // Wf2 tiles 0..7 of this hc
        __builtin_amdgcn_s_setprio(1);
#pragma unroll
        for (int tt = 0; tt < 4; tt++) {
          r0[tt] = MF(FRAG(B, 2 * tt), hbb, r0[tt]);
          r1[tt] = MF(FRAG(B, 2 * tt + 1), hbb, r1[tt]);
        }
        __builtin_amdgcn_s_setprio(0);
      }
      {
        const short* B = boundary();  // Wf2 tiles 8..15
        __builtin_amdgcn_s_setprio(1);
#pragma unroll
        for (int tt = 0; tt < 4; tt++) {
          r0[4 + tt] = MF(FRAG(B, 2 * tt), hbb, r0[4 + tt]);
          r1[4 + tt] = MF(FRAG(B, 2 * tt + 1), hbb, r1[4 + tt]);
        }
        __builtin_amdgcn_s_setprio(0);
      }
    }
    // ---- bias term of FFN residual: r += maskn * bf2 ----
#pragma unroll
    for (int kc = 0; kc < 8; kc++) {
      f32x4 b0 = *(const f32x4*)&P_bf2[32 * kc + 4 * g];
      f32x4 b1 = *(const f32x4*)&P_bf2[32 * kc + 16 + 4 * g];
#pragma unroll
      for (int c = 0; c < 4; c++) {
        r0[kc][c] += maskn * b0[c];
        r1[kc][c] += maskn * b1[c];
      }
    }

    // ---- candidate combine in global out ----
    if (sidx == 0) {
      float* op = outp + base + n * 256;
#pragma unroll
      for (int kc = 0; kc < 8; kc++) {
        f32x4 o0, o1;
#pragma unroll
        for (int c = 0; c < 4; c++) { o0[c] = w0 * r0[kc][c]; o1[c] = w0 * r1[kc][c]; }
        *(f32x4*)(op + 32 * kc + 4 * g) = o0;
        *(f32x4*)(op + 32 * kc + 16 + 4 * g) = o1;
      }
    } else if (sidx == 1 || sidx == 3) {
      float wc = (sidx == 1) ? w1 : w2;
      float* op = outp + base + n * 256;
#pragma unroll
      for (int kc = 0; kc < 8; kc++) {
        f32x4 o0 = *(f32x4*)(op + 32 * kc + 4 * g);
        f32x4 o1 = *(f32x4*)(op + 32 * kc + 16 + 4 * g);
#pragma unroll
        for (int c = 0; c < 4; c++) { o0[c] += wc * r0[kc][c]; o1[c] += wc * r1[kc][c]; }
        *(f32x4*)(op + 32 * kc + 4 * g) = o0;
        *(f32x4*)(op + 32 * kc + 16 + 4 * g) = o1;
      }
    }
  }
}

__global__ void finalize_kernel(const float* __restrict__ accum, float* __restrict__ dst) {
  const float inv = 1.f / 4096.f;
  float m0 = accum[0] * inv, m1 = accum[1] * inv, m2 = accum[2] * inv;
  const float u = 1.f / 3.f;
  float d0 = m0 - u, d1 = m1 - u, d2 = m2 - u;
  dst[0] = (d0 * d0 + d1 * d1 + d2 * d2) * (1.f / 3.f);
  dst[1] = accum[3] * inv;
}

extern "C" void kernel_launch(void* const* d_in, const int* in_sizes, int n_in,
                              void* d_out, int out_size, void* d_ws, size_t ws_size,
                              hipStream_t stream) {
  const float* s    = (const float*)d_in[0];
  const float* r    = (const float*)d_in[1];
  const float* Wd1  = (const float*)d_in[2];
  const float* bd1  = (const float*)d_in[3];
  const float* Wd2  = (const float*)d_in[4];
  const float* bd2  = (const float*)d_in[5];
  const float* Wa1  = (const float*)d_in[6];
  const float* ba1  = (const float*)d_in[7];
  const float* Wa2  = (const float*)d_in[8];
  const float* ba2  = (const float*)d_in[9];
  const float* Wsp  = (const float*)d_in[10];
  const float* ln1s = (const float*)d_in[11];
  const float* ln1b = (const float*)d_in[12];
  const float* Wq   = (const float*)d_in[13];
  const float* Wk   = (const float*)d_in[14];
  const float* Wv   = (const float*)d_in[15];
  const float* Wo   = (const float*)d_in[16];
  const float* ln2s = (const float*)d_in[17];
  const float* ln2b = (const float*)d_in[18];
  const float* Wf1  = (const float*)d_in[19];
  const float* bf1  = (const float*)d_in[20];
  const float* Wf2  = (const float*)d_in[21];
  const float* bf2  = (const float*)d_in[22];

  float* out = (float*)d_out;
  float* wsf = (float*)d_ws;
  float* mask   = wsf;
  float* sproj  = wsf + 65536;
  float* probsv = wsf + 65536 + 4096;
  float* accum  = wsf + 65536 + 4096 + 12288;
  short* pk     = (short*)(wsf + 131072);
  short* Wstream = pk;             // 786432 shorts (1536 x 1KB frags)
  short* PWa1    = pk + 786432;    // 32768
  short* PWd1    = pk + 819200;    // 131072

  pack_stream<<<384, 256, 0, stream>>>(Wq, Wk, Wv, Wo, Wf1, Wf2, Wstream);
  pack_weight<<<16, 256, 0, stream>>>(Wa1, PWa1, 256, 128);
  pack_weight<<<64, 256, 0, stream>>>(Wd1, PWd1, 1024, 128);

  init_accum_kernel<<<1, 64, 0, stream>>>(accum);
  sproj_kernel<<<NPOS, 256, 0, stream>>>(s, Wsp, sproj);
  difficulty_mfma<<<64, 256, 0, stream>>>(s, PWd1, bd1, Wd2, bd2, probsv, accum);
  slot_mask_mfma<<<NPOS / 4, 256, 0, stream>>>(r, PWa1, ba1, Wa2, ba2, sproj, mask);

  reason_all<<<NPOS / 4, 256, 0, stream>>>(r, mask, probsv, out, Wstream,
                                           ln1s, ln1b, ln2s, ln2b, bf1, bf2);

  finalize_kernel<<<1, 1, 0, stream>>>(accum, out + R_ELEMS);
}